// Round 5
// baseline (416.082 us; speedup 1.0000x reference)
//
#include <hip/hip_runtime.h>
#include <hip/hip_cooperative_groups.h>

namespace cg = cooperative_groups;

// Gabor renderer, round 5.
// r4 diagnosis: gather inner loop did 7 LDS broadcast reads/eval -> LDS-pipe
// bound (46.7us, VALUBusy 50%); plus ~30us per graph-captured launch (3 launches).
// Fixes:
//  (a) per-atom precompute so the hot loop is pure f32 (no f64, no LDS):
//      split om/SR = ohi(12-bit mantissa)+olo so k*ohi is EXACT in f32
//      (|k|<=1328<2^11); fold om*d0+phi/2pi into po. Phase err ~5e-7 rev.
//  (b) params packed 2xfloat4/atom in ws, read with wave-uniform index
//      (scalar-load path, no LDS pipe).
//  (c) ONE cooperative kernel: zero-counts / prep+bin / gather with
//      grid.sync() between phases -> 1 launch instead of 3.

constexpr double SR_D       = 24000.0;
constexpr double INV_SR_D   = 1.0 / 24000.0;
constexpr double INV_2PI_D  = 0.15915494309189535;
constexpr float  INV_SR_F   = 4.1666668e-5f;      // f32(1/24000)
constexpr int    HALF_MAX   = 1201;               // ceil(5*0.01*24000)+1
constexpr int    TILE_SHIFT = 7;
constexpr int    TILE       = 128;                // samples per tile = threads per block
constexpr int    CAP        = 160;                // per-tile atom capacity (mean ~99, max ~141)

// cos(2*pi*m) for m in [-0.5, 0.5]. Quadrant split; Taylor on [-pi/4, pi/4].
__device__ __forceinline__ float cos2pi(float m)
{
    float qf  = rintf(4.0f * m);
    float rem = fmaf(qf, -0.25f, m);          // [-0.125, 0.125]
    float th  = 6.28318530717958647f * rem;   // [-pi/4, pi/4]
    float t2  = th * th;
    float s = th * fmaf(t2, fmaf(t2, fmaf(t2, -1.98412701e-4f, 8.33333377e-3f),
                                  -0.166666672f), 1.0f);
    float c = fmaf(t2, fmaf(t2, fmaf(t2, fmaf(t2, 2.48015876e-5f, -1.38888892e-3f),
                                     4.16666679e-2f), -0.5f), 1.0f);
    int qm = ((int)qf) & 3;
    return (qm == 0) ? c : (qm == 1) ? -s : (qm == 2) ? -c : s;
}

__global__ __launch_bounds__(TILE)
void gabor_fused(const float* __restrict__ amp, const float* __restrict__ tau,
                 const float* __restrict__ omg, const float* __restrict__ sig,
                 const float* __restrict__ phi, const float* __restrict__ gam,
                 float4* __restrict__ pk0, float4* __restrict__ pk1,
                 int* __restrict__ counts, unsigned short* __restrict__ lists,
                 float* __restrict__ out, int num_samples, int n_atoms, int n_tiles)
{
    cg::grid_group grid = cg::this_grid();
    const int gid     = blockIdx.x * TILE + (int)threadIdx.x;
    const int gstride = gridDim.x * TILE;

    // ---- phase 0: zero tile counters (ws is poisoned 0xAA every call) ----
    for (int t = gid; t < n_tiles; t += gstride) counts[t] = 0;
    grid.sync();

    // ---- phase 1: per-atom param prep (f64, once per atom) + tile binning ----
    for (int a = gid; a < n_atoms; a += gstride) {
        double tu = (double)tau[a], om = (double)omg[a], sg = (double)sig[a];
        int center = (int)rint(tu * SR_D);
        // split q = om/SR into ohi (12-bit mantissa; k*ohi exact) + olo
        double q  = om * INV_SR_D;                       // in [0, 1/3)
        float  qf = (float)q;
        float ohi = __uint_as_float(__float_as_uint(qf) & 0xFFFFF000u);
        float olo = (float)(q - (double)ohi);            // |olo| <= ~8e-5
        double d0 = (double)center * INV_SR_D - tu;      // |d0| <= ~2.1e-5 s
        double pr = om * d0 + (double)phi[a] * INV_2PI_D;
        float  po = (float)(pr - floor(pr));             // [0,1)
        pk0[a] = make_float4(__int_as_float(center), ohi, olo, po);
        pk1[a] = make_float4((float)d0, (float)(0.5 * (double)gam[a]),
                             amp[a], 5.0f * sig[a]);
        int hw = (int)ceil(5.0 * sg * SR_D) + 1;
        hw = min(hw, HALF_MAX);
        int lo = max(center - hw, 0), hi = min(center + hw, num_samples - 1);
        if (lo <= hi) {
            int t0 = lo >> TILE_SHIFT, t1 = hi >> TILE_SHIFT;
            for (int t = t0; t <= t1; ++t) {
                int slot = atomicAdd(&counts[t], 1);
                if (slot < CAP) lists[t * CAP + slot] = (unsigned short)a;
            }
        }
    }
    grid.sync();

    // ---- phase 2: per-tile gather, pure f32, register accumulator ----
    const int tile = blockIdx.x;                 // gridDim.x == n_tiles
    const int cnt  = min(counts[tile], CAP);
    const int idx  = (tile << TILE_SHIFT) + (int)threadIdx.x;
    const int base = tile * CAP;
    float acc = 0.0f;
    for (int i = 0; i < cnt; ++i) {
        int a = (int)lists[base + i];            // wave-uniform index chain
        float4 q0 = pk0[a];                      // {center, ohi, olo, po}
        float4 q1 = pk1[a];                      // {d0, gmh, amp, smf=5sig}
        float kf  = (float)(idx - __float_as_int(q0.x));  // |k| <= 1328, exact
        float dtf = fmaf(kf, INV_SR_F, q1.x);
        // envelope: exp(-12.5*(dt/(5sig))^2); rcp rel err ~2e-7 -> harmless
        float z5  = dtf * __builtin_amdgcn_rcpf(q1.w);
        float env = __expf(-12.5f * z5 * z5);    // underflows to 0 for far lanes
        // phase (revolutions): fract(k*ohi) exact, small terms added after
        float f1 = kf * q0.y;                    // EXACT (11+12 bit product)
        float p  = f1 - floorf(f1);              // exact fract, [0,1)
        p = fmaf(kf, q0.z, p);                   // + k*olo      (|..|<=0.11)
        p = fmaf(q1.y, dtf * dtf, p);            // + 0.5*gam*dt^2 (|..|<~0.8)
        p = p + q0.w;                            // + po, p in (-1.1, 3.0)
        float m = p - rintf(p);                  // [-0.5, 0.5]
        float c = cos2pi(m);
        float am = (fabsf(dtf) <= q1.w) ? q1.z : 0.0f;   // window mask
        acc = fmaf(am * env, c, acc);
    }
    if (idx < num_samples) out[idx] = acc;
}

// ---------------- fallback: round-3 atomic scatter (proven-correct) ----------------
__global__ __launch_bounds__(256)
void gabor_scatter(const float* __restrict__ amp, const float* __restrict__ tau,
                   const float* __restrict__ omg, const float* __restrict__ sig,
                   const float* __restrict__ phi, const float* __restrict__ gam,
                   float* __restrict__ out, int num_samples)
{
    const int atom = blockIdx.x;
    const float  a    = amp[atom];
    const double tu   = (double)tau[atom];
    const double om   = (double)omg[atom];
    const double sg   = (double)sig[atom];
    const double phr  = (double)phi[atom] * INV_2PI_D;
    const double gm_h = 0.5 * (double)gam[atom];
    const int center = (int)rint(tu * SR_D);
    const double sm = 5.0 * sg;
    const double inv_sg = 1.0 / sg;
    int hw = (int)ceil(sm * SR_D) + 1;
    hw = min(hw, HALF_MAX);
    int lo = max(center - hw, 0);
    int hi = min(center + hw, num_samples - 1);
    for (int idx = lo + (int)threadIdx.x; idx <= hi; idx += 256) {
        double t  = (double)idx * INV_SR_D;
        double dt = t - tu;
        if (fabs(dt) <= sm) {
            double z   = dt * inv_sg;
            float  env = __expf((float)(-0.5 * z * z));
            double r = om * dt + gm_h * dt * dt + phr;
            double f = r - floor(r);
            float  m = (float)(f - 0.5);
            float  c = -cos2pi(m);
            atomicAdd(&out[idx], a * env * c);
        }
    }
}

extern "C" void kernel_launch(void* const* d_in, const int* in_sizes, int n_in,
                              void* d_out, int out_size, void* d_ws, size_t ws_size,
                              hipStream_t stream)
{
    const float* amp = (const float*)d_in[0];
    const float* tau = (const float*)d_in[1];
    const float* omg = (const float*)d_in[2];
    const float* sig = (const float*)d_in[3];
    const float* phi = (const float*)d_in[4];
    const float* gam = (const float*)d_in[5];
    const int N = in_sizes[0];            // 16384 atoms
    float* out = (float*)d_out;
    int ns = out_size;

    const int n_tiles = (out_size + TILE - 1) >> TILE_SHIFT;   // 1875
    auto aln = [](size_t x, size_t a) { return (x + a - 1) & ~(a - 1); };
    size_t pk0_off = 0;
    size_t pk1_off = aln(pk0_off + (size_t)N * 16, 16);
    size_t cnt_off = aln(pk1_off + (size_t)N * 16, 256);
    size_t lst_off = aln(cnt_off + (size_t)n_tiles * 4, 256);
    size_t ws_need = lst_off + (size_t)n_tiles * CAP * 2;      // ~1.13 MB

    if (ws_size >= ws_need && N <= 65535) {
        float4* pk0 = (float4*)((char*)d_ws + pk0_off);
        float4* pk1 = (float4*)((char*)d_ws + pk1_off);
        int*    cts = (int*)((char*)d_ws + cnt_off);
        unsigned short* lst = (unsigned short*)((char*)d_ws + lst_off);
        int na = N, nt = n_tiles;
        void* args[] = {(void*)&amp, (void*)&tau, (void*)&omg, (void*)&sig,
                        (void*)&phi, (void*)&gam, (void*)&pk0, (void*)&pk1,
                        (void*)&cts, (void*)&lst, (void*)&out,
                        (void*)&ns, (void*)&na, (void*)&nt};
        hipError_t e = hipLaunchCooperativeKernel((void*)gabor_fused,
                                                  dim3(n_tiles), dim3(TILE),
                                                  args, 0, stream);
        if (e == hipSuccess) return;
    }
    // fallback: proven round-3 path
    hipMemsetAsync(out, 0, (size_t)out_size * sizeof(float), stream);
    gabor_scatter<<<N, 256, 0, stream>>>(amp, tau, omg, sig, phi, gam, out, ns);
}

// Round 6
// 121.726 us; speedup vs baseline: 3.4182x; 3.4182x over previous
//
#include <hip/hip_runtime.h>

// Gabor renderer, round 6: ONE plain kernel, one block per 256-sample tile,
// everything block-local (no global scratch, no cooperative sync).
// r5 lesson: grid.sync() + cross-XCD visibility made every gather-loop load a
// serial LLC round trip (330us, VALUBusy 8.4%). Harness fixed overhead is
// ~60-90us regardless of launch count, so kernel time is the only lever.
//   Phase A: block scans all atoms (tau/sig, coalesced, L2-resident),
//            conservative f32 overlap test -> LDS list (LDS atomics).
//   Phase B: f64 param prep for the ~110 listed atoms -> 2xfloat4 in LDS.
//   Phase C: r5's numerically-validated pure-f32 loop (split ohi/olo phase,
//            |k|<2^11 so k*ohi exact), 2x ds_read_b128 broadcast per atom,
//            register accumulator, one coalesced store per sample.

constexpr double SR_D      = 24000.0;
constexpr double INV_SR_D  = 1.0 / 24000.0;
constexpr double INV_2PI_D = 0.15915494309189535;
constexpr float  INV_SR_F  = 4.1666668e-5f;   // f32(1/24000)
constexpr int    HALF_MAX  = 1201;
constexpr int    TILE      = 256;             // samples per tile == threads
constexpr int    CAP       = 256;             // per-tile atom capacity (mean ~109, max ~160)

// cos(2*pi*m) for m in [-0.5, 0.5]. Quadrant split; Taylor on [-pi/4, pi/4].
__device__ __forceinline__ float cos2pi(float m)
{
    float qf  = rintf(4.0f * m);
    float rem = fmaf(qf, -0.25f, m);          // [-0.125, 0.125]
    float th  = 6.28318530717958647f * rem;   // [-pi/4, pi/4]
    float t2  = th * th;
    float s = th * fmaf(t2, fmaf(t2, fmaf(t2, -1.98412701e-4f, 8.33333377e-3f),
                                  -0.166666672f), 1.0f);
    float c = fmaf(t2, fmaf(t2, fmaf(t2, fmaf(t2, 2.48015876e-5f, -1.38888892e-3f),
                                     4.16666679e-2f), -0.5f), 1.0f);
    int qm = ((int)qf) & 3;
    return (qm == 0) ? c : (qm == 1) ? -s : (qm == 2) ? -c : s;
}

__global__ __launch_bounds__(TILE)
void gabor_tile(const float* __restrict__ amp, const float* __restrict__ tau,
                const float* __restrict__ omg, const float* __restrict__ sig,
                const float* __restrict__ phi, const float* __restrict__ gam,
                float* __restrict__ out, int num_samples, int n_atoms)
{
    __shared__ int            s_cnt;
    __shared__ unsigned short s_id[CAP];
    __shared__ float4         s_q0[CAP];   // {center(bits), ohi, olo, po}
    __shared__ float4         s_q1[CAP];   // {d0, 0.5*gam, amp, 5*sig}

    const int tile0 = blockIdx.x << 8;
    const int tid   = (int)threadIdx.x;
    if (tid == 0) s_cnt = 0;
    __syncthreads();

    // ---- phase A: conservative overlap scan (superset of |dt|<=5sig hits) ----
    // center err <= 0.04 samples (f32 tau*SR); +2 margin is generous.
    const float lo_s = (float)(tile0 - 3);
    const float hi_s = (float)(tile0 + TILE - 1 + 3);
    for (int a = tid; a < n_atoms; a += TILE) {
        float c = tau[a] * 24000.0f;
        float w = fmaf(sig[a], 120000.0f, 2.0f);   // 5*sig*SR + margin
        if (c + w >= lo_s && c - w <= hi_s) {
            int slot = atomicAdd(&s_cnt, 1);
            if (slot < CAP) s_id[slot] = (unsigned short)a;
        }
    }
    __syncthreads();
    const int cnt = min(s_cnt, CAP);

    // ---- phase B: f64 prep for listed atoms (~110/block, negligible) ----
    for (int i = tid; i < cnt; i += TILE) {
        int a = (int)s_id[i];
        double tu = (double)tau[a], om = (double)omg[a];
        int center = (int)rint(tu * SR_D);
        double q  = om * INV_SR_D;                        // [0, 1/3)
        float  qf = (float)q;
        float ohi = __uint_as_float(__float_as_uint(qf) & 0xFFFFF000u);
        float olo = (float)(q - (double)ohi);             // |olo| <= ~8e-5
        double d0 = (double)center * INV_SR_D - tu;       // |d0| <= ~2.1e-5 s
        double pr = om * d0 + (double)phi[a] * INV_2PI_D;
        float  po = (float)(pr - floor(pr));              // [0,1)
        s_q0[i] = make_float4(__int_as_float(center), ohi, olo, po);
        s_q1[i] = make_float4((float)d0, (float)(0.5 * (double)gam[a]),
                              amp[a], 5.0f * sig[a]);
    }
    __syncthreads();

    // ---- phase C: pure-f32 gather, register accumulator ----
    const int idx = tile0 + tid;
    float acc = 0.0f;
    for (int i = 0; i < cnt; ++i) {
        float4 q0 = s_q0[i];                  // ds_read_b128 broadcast
        float4 q1 = s_q1[i];
        float kf  = (float)(idx - __float_as_int(q0.x));  // |k|<=1460<2^11, exact
        float dtf = fmaf(kf, INV_SR_F, q1.x);
        float z5  = dtf * __builtin_amdgcn_rcpf(q1.w);    // dt/(5sig)
        float env = __expf(-12.5f * z5 * z5);
        float f1  = kf * q0.y;                // EXACT (11x12-bit mantissa product)
        float p   = f1 - floorf(f1);          // exact fract
        p = fmaf(kf, q0.z, p);                // + k*olo       (|..|<=0.12)
        p = fmaf(q1.y, dtf * dtf, p);         // + 0.5*gam*dt^2 (|..|<~0.8)
        p = p + q0.w;                         // + po
        float m = p - rintf(p);               // [-0.5,0.5]
        float c = cos2pi(m);
        float am = (fabsf(dtf) <= q1.w) ? q1.z : 0.0f;    // exact window mask
        acc = fmaf(am * env, c, acc);
    }
    if (idx < num_samples) out[idx] = acc;
}

// ---------------- fallback (n_atoms > 65535): proven round-3 scatter ----------------
__global__ __launch_bounds__(256)
void gabor_scatter(const float* __restrict__ amp, const float* __restrict__ tau,
                   const float* __restrict__ omg, const float* __restrict__ sig,
                   const float* __restrict__ phi, const float* __restrict__ gam,
                   float* __restrict__ out, int num_samples)
{
    const int atom = blockIdx.x;
    const float  a    = amp[atom];
    const double tu   = (double)tau[atom];
    const double om   = (double)omg[atom];
    const double sg   = (double)sig[atom];
    const double phr  = (double)phi[atom] * INV_2PI_D;
    const double gm_h = 0.5 * (double)gam[atom];
    const int center = (int)rint(tu * SR_D);
    const double sm = 5.0 * sg;
    const double inv_sg = 1.0 / sg;
    int hw = (int)ceil(sm * SR_D) + 1;
    hw = min(hw, HALF_MAX);
    int lo = max(center - hw, 0);
    int hi = min(center + hw, num_samples - 1);
    for (int idx = lo + (int)threadIdx.x; idx <= hi; idx += 256) {
        double t  = (double)idx * INV_SR_D;
        double dt = t - tu;
        if (fabs(dt) <= sm) {
            double z   = dt * inv_sg;
            float  env = __expf((float)(-0.5 * z * z));
            double r = om * dt + gm_h * dt * dt + phr;
            double f = r - floor(r);
            float  m = (float)(f - 0.5);
            float  c = -cos2pi(m);
            atomicAdd(&out[idx], a * env * c);
        }
    }
}

extern "C" void kernel_launch(void* const* d_in, const int* in_sizes, int n_in,
                              void* d_out, int out_size, void* d_ws, size_t ws_size,
                              hipStream_t stream)
{
    const float* amp = (const float*)d_in[0];
    const float* tau = (const float*)d_in[1];
    const float* omg = (const float*)d_in[2];
    const float* sig = (const float*)d_in[3];
    const float* phi = (const float*)d_in[4];
    const float* gam = (const float*)d_in[5];
    const int N = in_sizes[0];            // 16384 atoms
    float* out = (float*)d_out;

    if (N <= 65535) {
        const int n_tiles = (out_size + TILE - 1) >> 8;   // 938
        gabor_tile<<<n_tiles, TILE, 0, stream>>>(amp, tau, omg, sig, phi, gam,
                                                 out, out_size, N);
    } else {
        hipMemsetAsync(out, 0, (size_t)out_size * sizeof(float), stream);
        gabor_scatter<<<N, 256, 0, stream>>>(amp, tau, omg, sig, phi, gam,
                                             out, out_size);
    }
}